// Round 1
// baseline (620.789 us; speedup 1.0000x reference)
//
#include <hip/hip_runtime.h>
#include <hip/hip_bf16.h>

#define B_    32
#define CIN   128
#define COUT  128
#define NN    128
#define PPAD  130   // padded p dimension (1 zero col each side)

typedef __attribute__((ext_vector_type(8))) short short8;
typedef __attribute__((ext_vector_type(4))) float float4v;

static __device__ inline unsigned short f2bf(float f) {
    union { float f; unsigned u; } v; v.f = f;
    unsigned u = v.u;
    unsigned r = u + 0x7FFFu + ((u >> 16) & 1u);   // RNE
    return (unsigned short)(r >> 16);
}

// ---------------------------------------------------------------------------
// x [B][C][N][N] f32  ->  xT [B][N(row)][PPAD][C] bf16, zero cols pp=0,129
// one block per (b, i): transpose a 128(c) x 128(p) tile
// ---------------------------------------------------------------------------
__global__ __launch_bounds__(256) void xpose_kernel(const float* __restrict__ x,
                                                    unsigned short* __restrict__ xT) {
    int b = blockIdx.x >> 7;
    int i = blockIdx.x & 127;
    __shared__ unsigned short tile[CIN * PPAD];   // [c][p], row stride 130 (33,280 B)
    int tid = threadIdx.x;
    const float* src = x + ((size_t)(b * CIN) * NN + i) * NN;  // x[b][0][i][0]
    #pragma unroll
    for (int e = 0; e < 64; ++e) {
        int idx = e * 256 + tid;
        int c = idx >> 7;
        int p = idx & 127;
        tile[c * PPAD + p] = f2bf(src[(size_t)c * (NN * NN) + p]);
    }
    __syncthreads();
    unsigned short* dst = xT + (size_t)(b * NN + i) * PPAD * CIN;
    // write pairs: element pair pi -> c2 = (pi&63)*2, p = pi>>6
    #pragma unroll
    for (int e = 0; e < 32; ++e) {
        int pi = e * 256 + tid;          // 0..8191
        int c2 = (pi & 63) * 2;
        int p  = pi >> 6;
        ushort2 v;
        v.x = tile[c2 * PPAD + p];
        v.y = tile[(c2 + 1) * PPAD + p];
        *(ushort2*)(dst + (size_t)(p + 1) * CIN + c2) = v;
    }
    // zero pad columns pp = 0 and pp = 129
    if (tid < 128) {
        dst[tid] = 0;
        dst[(size_t)129 * CIN + tid] = 0;
    }
}

// ---------------------------------------------------------------------------
// kernel [O][C][3][3] f32 -> kT [kd][O][C] bf16   (kd = k*3+d)
// ---------------------------------------------------------------------------
__global__ __launch_bounds__(256) void ktrans_kernel(const float* __restrict__ kern,
                                                     unsigned short* __restrict__ kT) {
    int idx = blockIdx.x * 256 + threadIdx.x;     // 0..147455
    if (idx >= COUT * CIN * 9) return;
    int c  = idx & 127;
    int t  = idx >> 7;
    int o  = t & 127;
    int kd = t >> 7;                              // 0..8
    int k = kd / 3, d = kd % 3;
    kT[idx] = f2bf(kern[(((size_t)o * CIN + c) * 3 + k) * 3 + d]);
}

// ---------------------------------------------------------------------------
// main: implicit GEMM, one block per (b, output row i); 4 waves, each 64o x 64p
// ---------------------------------------------------------------------------
__global__ __launch_bounds__(256) void conv_mfma_kernel(const unsigned short* __restrict__ xT,
                                                        const unsigned short* __restrict__ kT,
                                                        float* __restrict__ out) {
    int b   = blockIdx.x >> 7;
    int i   = blockIdx.x & 127;
    int tid = threadIdx.x;
    int lane = tid & 63;
    int wave = tid >> 6;
    int wr = wave >> 1;          // o half (0/1)
    int wc = wave & 1;           // p half (0/1)
    int l15 = lane & 15;
    int lg  = lane >> 4;         // 0..3  (k-group)

    float4v acc[4][4];
    #pragma unroll
    for (int m = 0; m < 4; ++m)
        #pragma unroll
        for (int n = 0; n < 4; ++n)
            acc[m][n] = (float4v)(0.0f);

    const int obase = wr * 64;
    const int pbase = wc * 64;

    #pragma unroll
    for (int kd = 0; kd < 9; ++kd) {
        const int k = kd / 3, d = kd % 3;
        const int row = i + k - 1;
        if (row < 0 || row >= NN) continue;      // block-uniform branch
        const unsigned short* xrow = xT + (size_t)(b * NN + row) * PPAD * CIN;
        const unsigned short* krow = kT + (size_t)kd * COUT * CIN;
        #pragma unroll
        for (int cc = 0; cc < 4; ++cc) {
            const int cbase = cc * 32 + lg * 8;
            short8 a[4], bt[4];
            #pragma unroll
            for (int m = 0; m < 4; ++m) {
                int o = obase + m * 16 + l15;
                a[m] = *(const short8*)(krow + o * CIN + cbase);
            }
            #pragma unroll
            for (int n = 0; n < 4; ++n) {
                int pp = pbase + n * 16 + l15 + d;       // padded col in [0,129]
                bt[n] = *(const short8*)(xrow + (size_t)pp * CIN + cbase);
            }
            #pragma unroll
            for (int m = 0; m < 4; ++m)
                #pragma unroll
                for (int n = 0; n < 4; ++n)
                    acc[m][n] = __builtin_amdgcn_mfma_f32_16x16x32_bf16(a[m], bt[n], acc[m][n], 0, 0, 0);
        }
    }

    // store: D col = lane&15 -> p, row = (lane>>4)*4 + r -> o
    float* op = out + ((size_t)(b * COUT) * NN + i) * NN;   // out[b][0][i][0]
    #pragma unroll
    for (int m = 0; m < 4; ++m) {
        #pragma unroll
        for (int n = 0; n < 4; ++n) {
            int p = pbase + n * 16 + l15;
            #pragma unroll
            for (int r = 0; r < 4; ++r) {
                int o = obase + m * 16 + lg * 4 + r;
                op[(size_t)o * (NN * NN) + p] = acc[m][n][r];
            }
        }
    }
}

// ---------------------------------------------------------------------------
// fallback: naive direct conv (only if workspace too small)
// ---------------------------------------------------------------------------
__global__ __launch_bounds__(256) void conv_naive_kernel(const float* __restrict__ x,
                                                         const float* __restrict__ kern,
                                                         float* __restrict__ out) {
    size_t idx = (size_t)blockIdx.x * 256 + threadIdx.x;
    int p = idx & 127;
    size_t t = idx >> 7;
    int i = t & 127; t >>= 7;
    int o = t & 127;
    int b = (int)(t >> 7);
    float s = 0.f;
    for (int c = 0; c < CIN; ++c) {
        #pragma unroll
        for (int k = 0; k < 3; ++k) {
            int r = i + k - 1;
            if (r < 0 || r >= NN) continue;
            #pragma unroll
            for (int d = 0; d < 3; ++d) {
                int q = p + d - 1;
                if (q < 0 || q >= NN) continue;
                s += kern[(((size_t)o * CIN + c) * 3 + k) * 3 + d]
                   * x[(((size_t)b * CIN + c) * NN + r) * NN + q];
            }
        }
    }
    out[idx] = s;
}

extern "C" void kernel_launch(void* const* d_in, const int* in_sizes, int n_in,
                              void* d_out, int out_size, void* d_ws, size_t ws_size,
                              hipStream_t stream) {
    const float* x    = (const float*)d_in[0];
    const float* kern = (const float*)d_in[1];
    float* out = (float*)d_out;

    const size_t xT_bytes = (size_t)B_ * NN * PPAD * CIN * 2;   // 136,314,880
    const size_t kT_bytes = (size_t)9 * COUT * CIN * 2;         //     294,912

    if (ws_size >= xT_bytes + kT_bytes) {
        unsigned short* xT = (unsigned short*)d_ws;
        unsigned short* kT = (unsigned short*)((char*)d_ws + xT_bytes);
        hipLaunchKernelGGL(xpose_kernel, dim3(B_ * NN), dim3(256), 0, stream, x, xT);
        hipLaunchKernelGGL(ktrans_kernel, dim3(576), dim3(256), 0, stream, kern, kT);
        hipLaunchKernelGGL(conv_mfma_kernel, dim3(B_ * NN), dim3(256), 0, stream, xT, kT, out);
    } else {
        hipLaunchKernelGGL(conv_naive_kernel, dim3(67108864 / 256), dim3(256), 0, stream,
                           x, kern, out);
    }
}

// Round 2
// 414.370 us; speedup vs baseline: 1.4982x; 1.4982x over previous
//
#include <hip/hip_runtime.h>
#include <hip/hip_bf16.h>

#define B_    32
#define CIN   128
#define COUT  128
#define NN    128
#define PPAD  130   // padded p dimension (1 zero col each side)

typedef __attribute__((ext_vector_type(8))) short short8;
typedef __attribute__((ext_vector_type(4))) float float4v;

static __device__ inline unsigned short f2bf(float f) {
    union { float f; unsigned u; } v; v.f = f;
    unsigned u = v.u;
    unsigned r = u + 0x7FFFu + ((u >> 16) & 1u);   // RNE
    return (unsigned short)(r >> 16);
}

// ---------------------------------------------------------------------------
// x [B][C][N][N] f32  ->  xT [B][N(row)][PPAD][C] bf16, zero cols pp=0,129
// one block per (b, i): transpose a 128(c) x 128(p) tile
// ---------------------------------------------------------------------------
__global__ __launch_bounds__(256) void xpose_kernel(const float* __restrict__ x,
                                                    unsigned short* __restrict__ xT) {
    int b = blockIdx.x >> 7;
    int i = blockIdx.x & 127;
    __shared__ unsigned short tile[CIN * PPAD];   // [c][p], row stride 130
    int tid = threadIdx.x;
    const float* src = x + ((size_t)(b * CIN) * NN + i) * NN;  // x[b][0][i][0]
    #pragma unroll
    for (int e = 0; e < 64; ++e) {
        int idx = e * 256 + tid;
        int c = idx >> 7;
        int p = idx & 127;
        tile[c * PPAD + p] = f2bf(src[(size_t)c * (NN * NN) + p]);
    }
    __syncthreads();
    unsigned short* dst = xT + (size_t)(b * NN + i) * PPAD * CIN;
    #pragma unroll
    for (int e = 0; e < 32; ++e) {
        int pi = e * 256 + tid;          // 0..8191
        int c2 = (pi & 63) * 2;
        int p  = pi >> 6;
        ushort2 v;
        v.x = tile[c2 * PPAD + p];
        v.y = tile[(c2 + 1) * PPAD + p];
        *(ushort2*)(dst + (size_t)(p + 1) * CIN + c2) = v;
    }
    if (tid < 128) {
        dst[tid] = 0;
        dst[(size_t)129 * CIN + tid] = 0;
    }
}

// ---------------------------------------------------------------------------
// kernel [O][C][3][3] f32 -> kT [kd][O][C] bf16   (kd = k*3+d)
// ---------------------------------------------------------------------------
__global__ __launch_bounds__(256) void ktrans_kernel(const float* __restrict__ kern,
                                                     unsigned short* __restrict__ kT) {
    int idx = blockIdx.x * 256 + threadIdx.x;     // 0..147455
    if (idx >= COUT * CIN * 9) return;
    int c  = idx & 127;
    int t  = idx >> 7;
    int o  = t & 127;
    int kd = t >> 7;                              // 0..8
    int k = kd / 3, d = kd % 3;
    kT[idx] = f2bf(kern[(((size_t)o * CIN + c) * 3 + k) * 3 + d]);
}

// ---------------------------------------------------------------------------
// main v2: one block per (b, row-pair i0,i0+1). 512 threads, 8 waves.
// x rows staged to LDS (swizzled); kT streamed from L2.
// wave tile: 64 o x 64 pixels (2 o-halves x {2 rows x 2 p-halves})
// ---------------------------------------------------------------------------
#define NSLOT (4 * PPAD * 16)          // 16B slots in LDS x-buffer = 8320
#define SLOTS_PER_ROW (PPAD * 16)      // 2080

__global__ __launch_bounds__(512, 2) void conv_mfma2_kernel(const unsigned short* __restrict__ xT,
                                                            const unsigned short* __restrict__ kT,
                                                            float* __restrict__ out) {
    __shared__ unsigned short xs[4 * PPAD * CIN];   // 133,120 B

    // bijective XCD swizzle: 2048 blocks, 8 XCDs, 256-block contiguous slabs
    int wg = blockIdx.x;
    int lb = (wg & 7) * 256 + (wg >> 3);
    int b  = lb >> 6;
    int i0 = (lb & 63) * 2;

    int tid = threadIdx.x;

    // ---- stage global rows i0-1 .. i0+2 (zero rows outside [0,128)) ----
    // content (r,pp,cslot) stored at position slot j = cslot ^ (pp&15)
    // -> staging at linear position j loads content cslot = j ^ (pp&15)
    {
        const unsigned short* xb = xT + (size_t)b * NN * PPAD * CIN;
        #pragma unroll
        for (int s = 0; s < 17; ++s) {
            int W = s * 512 + tid;
            if (W < NSLOT) {
                int r   = W / SLOTS_PER_ROW;       // 0..3
                int rem = W - r * SLOTS_PER_ROW;
                int pp  = rem >> 4;                // 0..129
                int j   = rem & 15;                // slot position in row
                int csl = j ^ (pp & 15);           // content c-slot
                int grow = i0 - 1 + r;             // -1..128
                short8 v;
                if (grow >= 0 && grow < NN) {
                    v = *(const short8*)(xb + ((size_t)grow * PPAD + pp) * CIN + csl * 8);
                } else {
                    v = (short8)(0);
                }
                *(short8*)(&xs[(size_t)W * 8]) = v;
            }
        }
    }
    __syncthreads();

    int lane = tid & 63;
    int wave = tid >> 6;
    int wr = wave >> 2;            // o half (0/1)
    int wc = wave & 3;             // 0..3 -> (row, p-half)
    int ri = wc >> 1;              // which output row of the pair
    int pb = (wc & 1) * 64;        // p base
    int ob = wr * 64;              // o base
    int l15 = lane & 15;
    int lg  = lane >> 4;           // 0..3

    float4v acc[4][4];
    #pragma unroll
    for (int m = 0; m < 4; ++m)
        #pragma unroll
        for (int n = 0; n < 4; ++n)
            acc[m][n] = (float4v)(0.0f);

    #pragma unroll
    for (int kd = 0; kd < 9; ++kd) {
        const int k = kd / 3, d = kd % 3;
        const int lrow = ri + k;                    // LDS row 0..3
        const unsigned short* krow = kT + (size_t)kd * COUT * CIN;
        #pragma unroll
        for (int cc = 0; cc < 4; ++cc) {
            short8 a[4], bt[4];
            #pragma unroll
            for (int m = 0; m < 4; ++m) {
                int o = ob + m * 16 + l15;
                a[m] = *(const short8*)(krow + (size_t)o * CIN + cc * 32 + lg * 8);
            }
            #pragma unroll
            for (int n = 0; n < 4; ++n) {
                int pp = pb + n * 16 + l15 + d;     // 0..129
                int slot = (cc * 4 + lg) ^ (pp & 15);
                bt[n] = *(const short8*)(&xs[((size_t)(lrow * PPAD + pp)) * CIN + slot * 8]);
            }
            #pragma unroll
            for (int m = 0; m < 4; ++m)
                #pragma unroll
                for (int n = 0; n < 4; ++n)
                    acc[m][n] = __builtin_amdgcn_mfma_f32_16x16x32_bf16(a[m], bt[n], acc[m][n], 0, 0, 0);
        }
    }

    // store: D col = lane&15 -> p, row = (lane>>4)*4 + r -> o
    float* op = out + ((size_t)(b * COUT) * NN + (i0 + ri)) * NN;
    #pragma unroll
    for (int m = 0; m < 4; ++m) {
        #pragma unroll
        for (int n = 0; n < 4; ++n) {
            int p = pb + n * 16 + l15;
            #pragma unroll
            for (int r = 0; r < 4; ++r) {
                int o = ob + m * 16 + lg * 4 + r;
                op[(size_t)o * (NN * NN) + p] = acc[m][n][r];
            }
        }
    }
}

// ---------------------------------------------------------------------------
// fallback: naive direct conv (only if workspace too small)
// ---------------------------------------------------------------------------
__global__ __launch_bounds__(256) void conv_naive_kernel(const float* __restrict__ x,
                                                         const float* __restrict__ kern,
                                                         float* __restrict__ out) {
    size_t idx = (size_t)blockIdx.x * 256 + threadIdx.x;
    int p = idx & 127;
    size_t t = idx >> 7;
    int i = t & 127; t >>= 7;
    int o = t & 127;
    int b = (int)(t >> 7);
    float s = 0.f;
    for (int c = 0; c < CIN; ++c) {
        #pragma unroll
        for (int k = 0; k < 3; ++k) {
            int r = i + k - 1;
            if (r < 0 || r >= NN) continue;
            #pragma unroll
            for (int d = 0; d < 3; ++d) {
                int q = p + d - 1;
                if (q < 0 || q >= NN) continue;
                s += kern[(((size_t)o * CIN + c) * 3 + k) * 3 + d]
                   * x[(((size_t)b * CIN + c) * NN + r) * NN + q];
            }
        }
    }
    out[idx] = s;
}

extern "C" void kernel_launch(void* const* d_in, const int* in_sizes, int n_in,
                              void* d_out, int out_size, void* d_ws, size_t ws_size,
                              hipStream_t stream) {
    const float* x    = (const float*)d_in[0];
    const float* kern = (const float*)d_in[1];
    float* out = (float*)d_out;

    const size_t xT_bytes = (size_t)B_ * NN * PPAD * CIN * 2;   // 136,314,880
    const size_t kT_bytes = (size_t)9 * COUT * CIN * 2;         //     294,912

    if (ws_size >= xT_bytes + kT_bytes) {
        unsigned short* xT = (unsigned short*)d_ws;
        unsigned short* kT = (unsigned short*)((char*)d_ws + xT_bytes);
        hipLaunchKernelGGL(xpose_kernel, dim3(B_ * NN), dim3(256), 0, stream, x, xT);
        hipLaunchKernelGGL(ktrans_kernel, dim3(576), dim3(256), 0, stream, kern, kT);
        hipLaunchKernelGGL(conv_mfma2_kernel, dim3(B_ * NN / 2), dim3(512), 0, stream, xT, kT, out);
    } else {
        hipLaunchKernelGGL(conv_naive_kernel, dim3(67108864 / 256), dim3(256), 0, stream,
                           x, kern, out);
    }
}